// Round 2
// baseline (3130.511 us; speedup 1.0000x reference)
//
#include <hip/hip_runtime.h>
#include <hip/hip_bf16.h>
#include <math.h>

#define B_ 2
#define S_ 2048
#define D_ 1024
#define H_ 16
#define HD_ 64
#define L_ 6
#define NTOK (B_*S_)

typedef unsigned short ushort_t;
typedef unsigned int uint_t;

typedef __attribute__((ext_vector_type(8))) short bf16x8;
typedef __attribute__((ext_vector_type(4))) float f32x4;

__device__ __forceinline__ float bf2f(ushort_t u) {
    return __uint_as_float(((uint_t)u) << 16);
}
__device__ __forceinline__ ushort_t f2bf(float f) {
    uint_t x = __float_as_uint(f);
    uint_t r = (x + 0x7FFFu + ((x >> 16) & 1u)) >> 16;
    return (ushort_t)r;
}

// async global->LDS, 16B per lane, dest = wave-uniform base + lane*16
__device__ __forceinline__ void gld_lds16(const ushort_t* g, ushort_t* l) {
    __builtin_amdgcn_global_load_lds(
        (const __attribute__((address_space(1))) unsigned int*)g,
        (__attribute__((address_space(3))) unsigned int*)l,
        16, 0, 0);
}

// ---------------- fp32 [K][N] -> bf16 [N][K] transpose-convert ----------------
__global__ __launch_bounds__(256) void cvtT_kernel(const float* __restrict__ in,
                                                   ushort_t* __restrict__ out,
                                                   int K, int N) {
    __shared__ float tile[32][33];
    int n0 = blockIdx.x * 32;
    int k0 = blockIdx.y * 32;
    int t = threadIdx.x;
    int tc = t & 31, tr = t >> 5;          // tr 0..7
#pragma unroll
    for (int i = 0; i < 4; i++) {
        int k = k0 + tr + i * 8;
        tile[tr + i * 8][tc] = in[(size_t)k * N + n0 + tc];
    }
    __syncthreads();
#pragma unroll
    for (int i = 0; i < 4; i++) {
        int n = n0 + tr + i * 8;
        out[(size_t)n * K + k0 + tc] = f2bf(tile[tc][tr + i * 8]);
    }
}

// ---------------- bf16 V transpose: qkv[tok][3072](V part) -> vT[b][h][hd][S] ----------------
__global__ __launch_bounds__(256) void vt_kernel(const ushort_t* __restrict__ v,
                                                 ushort_t* __restrict__ vt) {
    __shared__ ushort_t tile[32][34];
    int s0 = blockIdx.x * 32;
    int hd0 = (blockIdx.y & 1) * 32;
    int bh = blockIdx.y >> 1;              // 0..31
    int b = bh >> 4, h = bh & 15;
    int t = threadIdx.x;
    int tc = t & 31, tr = t >> 5;
    const ushort_t* src = v + (size_t)(b * S_ + s0) * 3072 + 2048 + h * 64 + hd0;
#pragma unroll
    for (int i = 0; i < 4; i++)
        tile[tr + i * 8][tc] = src[(size_t)(tr + i * 8) * 3072 + tc];
    __syncthreads();
    ushort_t* dst = vt + ((size_t)bh * 64 + hd0) * S_ + s0;
#pragma unroll
    for (int i = 0; i < 4; i++)
        dst[(size_t)(tr + i * 8) * S_ + tc] = tile[tc][tr + i * 8];
}

// ---------------- embedding + positional encoding ----------------
__global__ void embed_kernel(const int* __restrict__ x, const float* __restrict__ emb,
                             float* __restrict__ h, ushort_t* __restrict__ hb) {
    int row = blockIdx.x;            // 0..NTOK-1
    int s = row % S_;
    int tok = x[row];
    const float* erow = emb + (size_t)tok * D_;
    float* hrow = h + (size_t)row * D_;
    ushort_t* hbrow = hb + (size_t)row * D_;
    const float kExp = -2.0f * 13.287712379549449f / (float)D_;  // -2*log2(10000)/D
    for (int c = threadIdx.x; c < D_; c += blockDim.x) {
        float factor = exp2f(kExp * (float)c);
        float ang = (float)s * factor;
        float pe = (c & 1) ? cosf(ang) : sinf(ang);
        float v = erow[c] * 32.0f + pe;
        hrow[c] = v;
        hbrow[c] = f2bf(v);
    }
}

// ---------------- m97-structure bf16 MFMA GEMM ----------------
// C[M,N] = A[M,K](bf16 row-major) @ Bt[N,K]^T (+bias)(relu)
#define GEMM_OUT_BF16 1
#define GEMM_RELU 2

template<int BM>
__global__ __launch_bounds__(256) void gemm_kernel(
    const ushort_t* __restrict__ A, const ushort_t* __restrict__ Bt,
    const float* __restrict__ bias, void* __restrict__ out,
    int M, int N, int K, int flags)
{
    constexpr int MI = BM / 32;                // m-fragments per wave
    __shared__ __align__(16) ushort_t sA[BM * 32];
    __shared__ __align__(16) ushort_t sB[128 * 32];

    int t = threadIdx.x;
    int lane = t & 63, w = t >> 6;
    int ln15 = lane & 15, q = lane >> 4;
    int n0 = blockIdx.x * 128, m0 = blockIdx.y * BM;
    int wr = w >> 1, wc = w & 1;

    f32x4 acc[MI][4];
#pragma unroll
    for (int i = 0; i < MI; i++)
#pragma unroll
        for (int j = 0; j < 4; j++) acc[i][j] = (f32x4){0.f, 0.f, 0.f, 0.f};

    const ushort_t* aPtr = A + (size_t)(m0 + w * (BM / 4) + (lane >> 2)) * K + (lane & 3) * 8;
    const ushort_t* bPtr = Bt + (size_t)(n0 + w * 32 + (lane >> 2)) * K + (lane & 3) * 8;
    ushort_t* sAw = sA + w * (BM / 4) * 32;
    ushort_t* sBw = sB + w * 1024;

    for (int k0 = 0; k0 < K; k0 += 32) {
        __syncthreads();                       // prev tile's ds_reads done
        gld_lds16(aPtr, sAw);
        if constexpr (BM == 128) gld_lds16(aPtr + 16 * K, sAw + 512);
        gld_lds16(bPtr, sBw);
        gld_lds16(bPtr + 16 * K, sBw + 512);
        aPtr += 32; bPtr += 32;
        __syncthreads();                       // compiler drains vmcnt(0) here

        bf16x8 af[MI], bfr[4];
#pragma unroll
        for (int i = 0; i < MI; i++)
            af[i] = *(const bf16x8*)(sA + (wr * (BM / 2) + i * 16 + ln15) * 32 + q * 8);
#pragma unroll
        for (int i = 0; i < 4; i++)
            bfr[i] = *(const bf16x8*)(sB + (wc * 64 + i * 16 + ln15) * 32 + q * 8);
#pragma unroll
        for (int mi = 0; mi < MI; mi++)
#pragma unroll
            for (int ni = 0; ni < 4; ni++)
                acc[mi][ni] = __builtin_amdgcn_mfma_f32_16x16x32_bf16(
                    af[mi], bfr[ni], acc[mi][ni], 0, 0, 0);
    }

#pragma unroll
    for (int mi = 0; mi < MI; mi++) {
#pragma unroll
        for (int ni = 0; ni < 4; ni++) {
            int row = m0 + wr * (BM / 2) + mi * 16 + q * 4;
            int col = n0 + wc * 64 + ni * 16 + ln15;
            float bv = bias ? bias[col] : 0.f;
#pragma unroll
            for (int r = 0; r < 4; r++) {
                float v = acc[mi][ni][r] + bv;
                if (flags & GEMM_RELU) v = fmaxf(v, 0.f);
                if (flags & GEMM_OUT_BF16)
                    ((ushort_t*)out)[(size_t)(row + r) * N + col] = f2bf(v);
                else
                    ((float*)out)[(size_t)(row + r) * N + col] = v;
            }
        }
    }
}

// ---------------- MFMA flash attention, zero-staging version ----------------
// Q,K from fused qkv buffer (stride 3072); V from transposed vT [bh][hd][S].
// No K/V LDS staging, no barriers: K/V tiles are L2-resident (XCD-chunked swizzle
// keeps 4 (b,h) pairs = 2 MB per XCD L2). Only per-wave P buffer in LDS.
#define SKP 72   // LDS row stride (elems); 144 B keeps b128 16B-aligned

__global__ __launch_bounds__(256) void attn_kernel(
    const ushort_t* __restrict__ Qm, const ushort_t* __restrict__ Km,
    const ushort_t* __restrict__ Vt, ushort_t* __restrict__ O)
{
    __shared__ __align__(16) ushort_t sP[4][16 * SKP]; // per-wave P [qrow][key]

    int t = threadIdx.x;
    int w = t >> 6, lane = t & 63;
    int ln15 = lane & 15, q = lane >> 4;

    // XCD-chunked bijective swizzle: 1024 blocks, 128 per XCD = 4 (b,h) pairs
    int wg = blockIdx.x;
    int lin = (wg & 7) * 128 + (wg >> 3);
    int bh = lin >> 5;                 // 0..31
    int qblk = lin & 31;
    int b = bh >> 4, hh = bh & 15;
    int q0 = qblk * 64;

    const size_t base  = (size_t)b * S_ * 3072 + hh * HD_;
    const size_t vbase = (size_t)bh * HD_ * S_;
    const size_t obase = (size_t)b * S_ * D_ + hh * HD_;

    // Q fragments (A layout): row m = ln15 (of this wave's 16 rows), k = q*8+j (+32)
    bf16x8 aq[2];
    {
        const ushort_t* qrow = Qm + base + (size_t)(q0 + w * 16 + ln15) * 3072;
        aq[0] = *(const bf16x8*)(qrow + q * 8);
        aq[1] = *(const bf16x8*)(qrow + 32 + q * 8);
    }

    f32x4 accO[4];
#pragma unroll
    for (int i = 0; i < 4; i++) accO[i] = (f32x4){0.f, 0.f, 0.f, 0.f};
    float mrow[4] = {-1e30f, -1e30f, -1e30f, -1e30f};
    float lrow[4] = {0.f, 0.f, 0.f, 0.f};

    for (int k0 = 0; k0 < S_; k0 += 64) {
        // scores: S[16 q x 64 keys] per wave; K B-fragments straight from global
        f32x4 sc[4];
#pragma unroll
        for (int nb = 0; nb < 4; nb++) {
            const ushort_t* krow = Km + base + (size_t)(k0 + nb * 16 + ln15) * 3072;
            bf16x8 bk0 = *(const bf16x8*)(krow + q * 8);
            bf16x8 bk1 = *(const bf16x8*)(krow + 32 + q * 8);
            f32x4 z = (f32x4){0.f, 0.f, 0.f, 0.f};
            z = __builtin_amdgcn_mfma_f32_16x16x32_bf16(aq[0], bk0, z, 0, 0, 0);
            z = __builtin_amdgcn_mfma_f32_16x16x32_bf16(aq[1], bk1, z, 0, 0, 0);
            sc[nb] = z;
        }

        // online softmax update (per q-row r; lane holds cols ln15+16nb)
        float p[4][4];
#pragma unroll
        for (int r = 0; r < 4; r++) {
            float s0 = sc[0][r] * 0.125f, s1 = sc[1][r] * 0.125f;
            float s2 = sc[2][r] * 0.125f, s3 = sc[3][r] * 0.125f;
            float pm = fmaxf(fmaxf(s0, s1), fmaxf(s2, s3));
#pragma unroll
            for (int off = 1; off < 16; off <<= 1)
                pm = fmaxf(pm, __shfl_xor(pm, off));
            float mnew = fmaxf(mrow[r], pm);
            float alpha = __expf(mrow[r] - mnew);
            mrow[r] = mnew;
            float p0 = __expf(s0 - mnew), p1 = __expf(s1 - mnew);
            float p2 = __expf(s2 - mnew), p3 = __expf(s3 - mnew);
            p[0][r] = p0; p[1][r] = p1; p[2][r] = p2; p[3][r] = p3;
            lrow[r] = lrow[r] * alpha + (p0 + p1 + p2 + p3);
            accO[0][r] *= alpha; accO[1][r] *= alpha;
            accO[2][r] *= alpha; accO[3][r] *= alpha;
        }

        // P -> per-wave LDS (C layout positions), reload in A layout. No barrier.
#pragma unroll
        for (int nb = 0; nb < 4; nb++)
#pragma unroll
            for (int r = 0; r < 4; r++)
                sP[w][(q * 4 + r) * SKP + nb * 16 + ln15] = f2bf(p[nb][r]);

        // PV: O[16 q x 64 hd] += P[16x64] @ V[64 keys x 64 hd]; V^T from global
#pragma unroll
        for (int c = 0; c < 2; c++) {
            bf16x8 ap = *(const bf16x8*)(&sP[w][ln15 * SKP + c * 32 + q * 8]);
#pragma unroll
            for (int nhd = 0; nhd < 4; nhd++) {
                const ushort_t* vrow = Vt + vbase + (size_t)(nhd * 16 + ln15) * S_
                                       + k0 + c * 32 + q * 8;
                bf16x8 bv = *(const bf16x8*)vrow;
                accO[nhd] = __builtin_amdgcn_mfma_f32_16x16x32_bf16(ap, bv, accO[nhd], 0, 0, 0);
            }
        }
    }

    // final row-sum reduce across the 16-lane col group, then write O
    float inv[4];
#pragma unroll
    for (int r = 0; r < 4; r++) {
        float l = lrow[r];
#pragma unroll
        for (int off = 1; off < 16; off <<= 1)
            l += __shfl_xor(l, off);
        inv[r] = 1.0f / l;
    }
    ushort_t* ob = O + obase;
#pragma unroll
    for (int nhd = 0; nhd < 4; nhd++)
#pragma unroll
        for (int r = 0; r < 4; r++)
            ob[(size_t)(q0 + w * 16 + q * 4 + r) * D_ + nhd * 16 + ln15] =
                f2bf(accO[nhd][r] * inv[r]);
}

// ---------------- fused residual-add + LayerNorm (fp32 + bf16 outputs) ----------------
__global__ __launch_bounds__(256) void ln_add_kernel(
    const float* __restrict__ a, const float* __restrict__ bres,
    const float* __restrict__ g, const float* __restrict__ be,
    float* __restrict__ of, ushort_t* __restrict__ ob)
{
    int row = blockIdx.x;
    int t = threadIdx.x;
    const float* ar = a + (size_t)row * D_;
    const float* br = bres + (size_t)row * D_;
    float x[4];
    float s = 0.f, sq = 0.f;
#pragma unroll
    for (int i = 0; i < 4; i++) {
        int c = t + i * 256;
        float v = ar[c] + br[c];
        x[i] = v; s += v; sq += v * v;
    }
#pragma unroll
    for (int off = 32; off; off >>= 1) {
        s += __shfl_xor(s, off);
        sq += __shfl_xor(sq, off);
    }
    __shared__ float rs[4], rq[4];
    int w = t >> 6;
    if ((t & 63) == 0) { rs[w] = s; rq[w] = sq; }
    __syncthreads();
    s = rs[0] + rs[1] + rs[2] + rs[3];
    sq = rq[0] + rq[1] + rq[2] + rq[3];
    float mu = s * (1.0f / D_);
    float var = sq * (1.0f / D_) - mu * mu;
    float rstd = rsqrtf(var + 1e-5f);
#pragma unroll
    for (int i = 0; i < 4; i++) {
        int c = t + i * 256;
        float y = (x[i] - mu) * rstd * g[c] + be[c];
        of[(size_t)row * D_ + c] = y;
        ob[(size_t)row * D_ + c] = f2bf(y);
    }
}

extern "C" void kernel_launch(void* const* d_in, const int* in_sizes, int n_in,
                              void* d_out, int out_size, void* d_ws, size_t ws_size,
                              hipStream_t stream) {
    const int*   x    = (const int*)d_in[0];
    const float* emb  = (const float*)d_in[1];
    const float* Wq   = (const float*)d_in[2];
    const float* Wk   = (const float*)d_in[3];
    const float* Wv   = (const float*)d_in[4];
    const float* Wo   = (const float*)d_in[5];
    const float* bo   = (const float*)d_in[6];
    const float* ln1g = (const float*)d_in[7];
    const float* ln1b = (const float*)d_in[8];
    const float* W1   = (const float*)d_in[9];
    const float* b1   = (const float*)d_in[10];
    const float* W2   = (const float*)d_in[11];
    const float* b2   = (const float*)d_in[12];
    const float* ln2g = (const float*)d_in[13];
    const float* ln2b = (const float*)d_in[14];

    char* ws = (char*)d_ws;
    float*    h    = (float*)(ws + 0);             // 16 MB fp32 residual
    ushort_t* hb   = (ushort_t*)(ws + 16777216);   // 8 MB bf16 h
    float*    t0   = (float*)(ws + 25165824);      // 16 MB fp32 gemm out
    ushort_t* vtb  = (ushort_t*)(ws + 25165824);   // 8 MB V^T, overlaps t0 (dead then)
    float*    n1   = (float*)(ws + 41943040);      // 16 MB fp32 n1
    ushort_t* n1b  = (ushort_t*)(ws + 58720256);   // 8 MB bf16 n1
    ushort_t* qkvb = (ushort_t*)(ws + 67108864);   // 24 MB fused qkv [M][3072]
    ushort_t* ab   = (ushort_t*)(ws + 92274688);   // 8 MB attn out
    ushort_t* ff1  = (ushort_t*)(ws + 67108864);   // 32 MB, overlaps dead qkv/ab
    ushort_t* wqkvT= (ushort_t*)(ws + 100663296);  // 6 MB [3072][1024] bf16 (q,k,v stacked)
    ushort_t* woT  = (ushort_t*)(ws + 106954752);  // 2 MB [1024][1024]
    ushort_t* w1T  = (ushort_t*)(ws + 109051904);  // 8 MB [4096][1024]
    ushort_t* w2T  = (ushort_t*)(ws + 117440512);  // 8 MB [1024][4096]  (total 120 MB)

    embed_kernel<<<NTOK, 256, 0, stream>>>(x, emb, h, hb);

    for (int l = 0; l < L_; l++) {
        const float* Wq_l = Wq + (size_t)l * D_ * D_;
        const float* Wk_l = Wk + (size_t)l * D_ * D_;
        const float* Wv_l = Wv + (size_t)l * D_ * D_;
        const float* Wo_l = Wo + (size_t)l * D_ * D_;
        const float* bo_l = bo + (size_t)l * D_;
        const float* W1_l = W1 + (size_t)l * D_ * 4 * D_;
        const float* b1_l = b1 + (size_t)l * 4 * D_;
        const float* W2_l = W2 + (size_t)l * 4 * D_ * D_;
        const float* b2_l = b2 + (size_t)l * D_;

        // weight transpose-convert: [K][N] fp32 -> [N][K] bf16
        cvtT_kernel<<<dim3(32, 32), 256, 0, stream>>>(Wq_l, wqkvT,                 1024, 1024);
        cvtT_kernel<<<dim3(32, 32), 256, 0, stream>>>(Wk_l, wqkvT + 1024 * 1024,   1024, 1024);
        cvtT_kernel<<<dim3(32, 32), 256, 0, stream>>>(Wv_l, wqkvT + 2048 * 1024,   1024, 1024);
        cvtT_kernel<<<dim3(32, 32), 256, 0, stream>>>(Wo_l, woT,                   1024, 1024);
        cvtT_kernel<<<dim3(128, 32), 256, 0, stream>>>(W1_l, w1T,                  1024, 4096);
        cvtT_kernel<<<dim3(32, 128), 256, 0, stream>>>(W2_l, w2T,                  4096, 1024);

        // fused QKV projection: [4096,1024] @ [1024,3072] -> [4096,3072] bf16
        gemm_kernel<128><<<dim3(3072 / 128, NTOK / 128), 256, 0, stream>>>(
            hb, wqkvT, nullptr, qkvb, NTOK, 3072, 1024, GEMM_OUT_BF16);

        // V^T for the attention PV B-operand
        vt_kernel<<<dim3(S_ / 32, 64), 256, 0, stream>>>(qkvb, vtb);

        attn_kernel<<<1024, 256, 0, stream>>>(qkvb, qkvb + 1024, vtb, ab);

        gemm_kernel<64><<<dim3(1024 / 128, NTOK / 64), 256, 0, stream>>>(
            ab, woT, bo_l, t0, NTOK, 1024, 1024, 0);
        ln_add_kernel<<<NTOK, 256, 0, stream>>>(t0, h, ln1g + l * D_, ln1b + l * D_, n1, n1b);

        gemm_kernel<128><<<dim3(4096 / 128, NTOK / 128), 256, 0, stream>>>(
            n1b, w1T, b1_l, ff1, NTOK, 4096, 1024, GEMM_OUT_BF16 | GEMM_RELU);
        gemm_kernel<64><<<dim3(1024 / 128, NTOK / 64), 256, 0, stream>>>(
            ff1, w2T, b2_l, t0, NTOK, 1024, 4096, 0);

        float* of = (l == L_ - 1) ? (float*)d_out : h;
        ln_add_kernel<<<NTOK, 256, 0, stream>>>(t0, n1, ln2g + l * D_, ln2b + l * D_, of, hb);
    }
}

// Round 3
// 2347.465 us; speedup vs baseline: 1.3336x; 1.3336x over previous
//
#include <hip/hip_runtime.h>
#include <hip/hip_bf16.h>
#include <math.h>

#define B_ 2
#define S_ 2048
#define D_ 1024
#define H_ 16
#define HD_ 64
#define L_ 6
#define NTOK (B_*S_)

typedef unsigned short ushort_t;
typedef unsigned int uint_t;

typedef __attribute__((ext_vector_type(8))) short bf16x8;
typedef __attribute__((ext_vector_type(4))) float f32x4;

__device__ __forceinline__ float bf2f(ushort_t u) {
    return __uint_as_float(((uint_t)u) << 16);
}
__device__ __forceinline__ ushort_t f2bf(float f) {
    uint_t x = __float_as_uint(f);
    uint_t r = (x + 0x7FFFu + ((x >> 16) & 1u)) >> 16;
    return (ushort_t)r;
}
// packed f32 pair -> 2x bf16 (RNE), single instruction
__device__ __forceinline__ uint_t f2bf_pk(float lo, float hi) {
    uint_t r;
    asm("v_cvt_pk_bf16_f32 %0, %1, %2" : "=v"(r) : "v"(lo), "v"(hi));
    return r;
}
// raw v_exp_f32 (2^x)
__device__ __forceinline__ float fexp2(float x) {
    float r;
    asm("v_exp_f32 %0, %1" : "=v"(r) : "v"(x));
    return r;
}

// async global->LDS, 16B per lane, dest = wave-uniform base + lane*16
__device__ __forceinline__ void gld_lds16(const ushort_t* g, ushort_t* l) {
    __builtin_amdgcn_global_load_lds(
        (const __attribute__((address_space(1))) unsigned int*)g,
        (__attribute__((address_space(3))) unsigned int*)l,
        16, 0, 0);
}

// ---------------- fp32 [K][N] -> bf16 [N][K] transpose-convert ----------------
__global__ __launch_bounds__(256) void cvtT_kernel(const float* __restrict__ in,
                                                   ushort_t* __restrict__ out,
                                                   int K, int N) {
    __shared__ float tile[32][33];
    int n0 = blockIdx.x * 32;
    int k0 = blockIdx.y * 32;
    int t = threadIdx.x;
    int tc = t & 31, tr = t >> 5;          // tr 0..7
#pragma unroll
    for (int i = 0; i < 4; i++) {
        int k = k0 + tr + i * 8;
        tile[tr + i * 8][tc] = in[(size_t)k * N + n0 + tc];
    }
    __syncthreads();
#pragma unroll
    for (int i = 0; i < 4; i++) {
        int n = n0 + tr + i * 8;
        out[(size_t)n * K + k0 + tc] = f2bf(tile[tc][tr + i * 8]);
    }
}

// ---------------- bf16 V transpose: qkv[tok][3072](V part) -> vT[b][h][hd][S] ----------------
__global__ __launch_bounds__(256) void vt_kernel(const ushort_t* __restrict__ v,
                                                 ushort_t* __restrict__ vt) {
    __shared__ ushort_t tile[32][34];
    int s0 = blockIdx.x * 32;
    int hd0 = (blockIdx.y & 1) * 32;
    int bh = blockIdx.y >> 1;              // 0..31
    int b = bh >> 4, h = bh & 15;
    int t = threadIdx.x;
    int tc = t & 31, tr = t >> 5;
    const ushort_t* src = v + (size_t)(b * S_ + s0) * 3072 + 2048 + h * 64 + hd0;
#pragma unroll
    for (int i = 0; i < 4; i++)
        tile[tr + i * 8][tc] = src[(size_t)(tr + i * 8) * 3072 + tc];
    __syncthreads();
    ushort_t* dst = vt + ((size_t)bh * 64 + hd0) * S_ + s0;
#pragma unroll
    for (int i = 0; i < 4; i++)
        dst[(size_t)(tr + i * 8) * S_ + tc] = tile[tc][tr + i * 8];
}

// ---------------- embedding + positional encoding ----------------
__global__ void embed_kernel(const int* __restrict__ x, const float* __restrict__ emb,
                             float* __restrict__ h, ushort_t* __restrict__ hb) {
    int row = blockIdx.x;            // 0..NTOK-1
    int s = row % S_;
    int tok = x[row];
    const float* erow = emb + (size_t)tok * D_;
    float* hrow = h + (size_t)row * D_;
    ushort_t* hbrow = hb + (size_t)row * D_;
    const float kExp = -2.0f * 13.287712379549449f / (float)D_;  // -2*log2(10000)/D
    for (int c = threadIdx.x; c < D_; c += blockDim.x) {
        float factor = exp2f(kExp * (float)c);
        float ang = (float)s * factor;
        float pe = (c & 1) ? cosf(ang) : sinf(ang);
        float v = erow[c] * 32.0f + pe;
        hrow[c] = v;
        hbrow[c] = f2bf(v);
    }
}

// ---------------- m97-structure bf16 MFMA GEMM ----------------
// C[M,N] = A[M,K](bf16 row-major) @ Bt[N,K]^T (+bias)(relu)
#define GEMM_OUT_BF16 1
#define GEMM_RELU 2

template<int BM>
__global__ __launch_bounds__(256) void gemm_kernel(
    const ushort_t* __restrict__ A, const ushort_t* __restrict__ Bt,
    const float* __restrict__ bias, void* __restrict__ out,
    int M, int N, int K, int flags)
{
    constexpr int MI = BM / 32;                // m-fragments per wave
    __shared__ __align__(16) ushort_t sA[BM * 32];
    __shared__ __align__(16) ushort_t sB[128 * 32];

    int t = threadIdx.x;
    int lane = t & 63, w = t >> 6;
    int ln15 = lane & 15, q = lane >> 4;
    int n0 = blockIdx.x * 128, m0 = blockIdx.y * BM;
    int wr = w >> 1, wc = w & 1;

    f32x4 acc[MI][4];
#pragma unroll
    for (int i = 0; i < MI; i++)
#pragma unroll
        for (int j = 0; j < 4; j++) acc[i][j] = (f32x4){0.f, 0.f, 0.f, 0.f};

    const ushort_t* aPtr = A + (size_t)(m0 + w * (BM / 4) + (lane >> 2)) * K + (lane & 3) * 8;
    const ushort_t* bPtr = Bt + (size_t)(n0 + w * 32 + (lane >> 2)) * K + (lane & 3) * 8;
    ushort_t* sAw = sA + w * (BM / 4) * 32;
    ushort_t* sBw = sB + w * 1024;

    for (int k0 = 0; k0 < K; k0 += 32) {
        __syncthreads();                       // prev tile's ds_reads done
        gld_lds16(aPtr, sAw);
        if constexpr (BM == 128) gld_lds16(aPtr + 16 * K, sAw + 512);
        gld_lds16(bPtr, sBw);
        gld_lds16(bPtr + 16 * K, sBw + 512);
        aPtr += 32; bPtr += 32;
        __syncthreads();                       // compiler drains vmcnt(0) here

        bf16x8 af[MI], bfr[4];
#pragma unroll
        for (int i = 0; i < MI; i++)
            af[i] = *(const bf16x8*)(sA + (wr * (BM / 2) + i * 16 + ln15) * 32 + q * 8);
#pragma unroll
        for (int i = 0; i < 4; i++)
            bfr[i] = *(const bf16x8*)(sB + (wc * 64 + i * 16 + ln15) * 32 + q * 8);
#pragma unroll
        for (int mi = 0; mi < MI; mi++)
#pragma unroll
            for (int ni = 0; ni < 4; ni++)
                acc[mi][ni] = __builtin_amdgcn_mfma_f32_16x16x32_bf16(
                    af[mi], bfr[ni], acc[mi][ni], 0, 0, 0);
    }

#pragma unroll
    for (int mi = 0; mi < MI; mi++) {
#pragma unroll
        for (int ni = 0; ni < 4; ni++) {
            int row = m0 + wr * (BM / 2) + mi * 16 + q * 4;
            int col = n0 + wc * 64 + ni * 16 + ln15;
            float bv = bias ? bias[col] : 0.f;
#pragma unroll
            for (int r = 0; r < 4; r++) {
                float v = acc[mi][ni][r] + bv;
                if (flags & GEMM_RELU) v = fmaxf(v, 0.f);
                if (flags & GEMM_OUT_BF16)
                    ((ushort_t*)out)[(size_t)(row + r) * N + col] = f2bf(v);
                else
                    ((float*)out)[(size_t)(row + r) * N + col] = v;
            }
        }
    }
}

// ---------------- MFMA flash attention (staged K + staged V^T) ----------------
// Q,K from fused qkv (stride 3072); V from transposed vT [bh][hd][S].
// r1-proven staged structure; V^T staged via b128 (no scalar transpose);
// softmax in exp2 domain; P->bf16 via packed cvt.
#define SKP 72   // LDS row stride (elems); 144 B keeps b128 16B-aligned
#define KSC 0.18033688011112042f   // 0.125 * log2(e)

__global__ __launch_bounds__(256) void attn_kernel(
    const ushort_t* __restrict__ Qm, const ushort_t* __restrict__ Km,
    const ushort_t* __restrict__ Vt, ushort_t* __restrict__ O)
{
    __shared__ __align__(16) ushort_t sK[64 * SKP];    // [key][hd]
    __shared__ __align__(16) ushort_t sVt[64 * SKP];   // [hd][key]
    __shared__ __align__(16) ushort_t sP[4][16 * SKP]; // per-wave P [qrow][key]

    int t = threadIdx.x;
    int w = t >> 6, lane = t & 63;
    int ln15 = lane & 15, q = lane >> 4;
    int b = blockIdx.z, hh = blockIdx.y;
    int q0 = blockIdx.x * 64;

    const size_t base  = (size_t)b * S_ * 3072 + hh * HD_;
    const size_t vbase = (size_t)(b * H_ + hh) * HD_ * S_;
    const size_t obase = (size_t)b * S_ * D_ + hh * HD_;

    // Q fragments (A layout): row m = ln15 (of this wave's 16 rows), k = q*8+j (+32)
    bf16x8 aq[2];
    {
        const ushort_t* qrow = Qm + base + (size_t)(q0 + w * 16 + ln15) * 3072;
        aq[0] = *(const bf16x8*)(qrow + q * 8);
        aq[1] = *(const bf16x8*)(qrow + 32 + q * 8);
    }

    f32x4 accO[4];
#pragma unroll
    for (int i = 0; i < 4; i++) accO[i] = (f32x4){0.f, 0.f, 0.f, 0.f};
    float mrow[4] = {-1e30f, -1e30f, -1e30f, -1e30f};
    float lrow[4] = {0.f, 0.f, 0.f, 0.f};

    // staging indices: 8 lanes cover one 128B row chunk
    int krow = t >> 3, kcol = (t & 7) * 8;   // K tile rows (keys), V^T tile rows (hd)

    for (int k0 = 0; k0 < S_; k0 += 64) {
        uint4 kv0 = *(const uint4*)(Km + base + (size_t)(k0 + krow) * 3072 + kcol);
        uint4 kv1 = *(const uint4*)(Km + base + (size_t)(k0 + 32 + krow) * 3072 + kcol);
        uint4 vv0 = *(const uint4*)(Vt + vbase + (size_t)krow * S_ + k0 + kcol);
        uint4 vv1 = *(const uint4*)(Vt + vbase + (size_t)(krow + 32) * S_ + k0 + kcol);
        __syncthreads();   // all waves done reading previous tile
        *(uint4*)(&sK[krow * SKP + kcol]) = kv0;
        *(uint4*)(&sK[(krow + 32) * SKP + kcol]) = kv1;
        *(uint4*)(&sVt[krow * SKP + kcol]) = vv0;
        *(uint4*)(&sVt[(krow + 32) * SKP + kcol]) = vv1;
        __syncthreads();

        // scores: S[16 q x 64 keys] per wave, C layout (row=4q+r, col=key nb*16+ln15)
        f32x4 sc[4];
#pragma unroll
        for (int nb = 0; nb < 4; nb++) {
            bf16x8 bk0 = *(const bf16x8*)(&sK[(nb * 16 + ln15) * SKP + q * 8]);
            bf16x8 bk1 = *(const bf16x8*)(&sK[(nb * 16 + ln15) * SKP + 32 + q * 8]);
            f32x4 z = (f32x4){0.f, 0.f, 0.f, 0.f};
            z = __builtin_amdgcn_mfma_f32_16x16x32_bf16(aq[0], bk0, z, 0, 0, 0);
            z = __builtin_amdgcn_mfma_f32_16x16x32_bf16(aq[1], bk1, z, 0, 0, 0);
            sc[nb] = z;
        }

        // online softmax (exp2 domain); lane holds cols ln15+16nb of rows q*4+r
        float p[4][4];
#pragma unroll
        for (int r = 0; r < 4; r++) {
            float s0 = sc[0][r] * KSC, s1 = sc[1][r] * KSC;
            float s2 = sc[2][r] * KSC, s3 = sc[3][r] * KSC;
            float pm = fmaxf(fmaxf(s0, s1), fmaxf(s2, s3));
#pragma unroll
            for (int off = 1; off < 16; off <<= 1)
                pm = fmaxf(pm, __shfl_xor(pm, off));
            float mnew = fmaxf(mrow[r], pm);
            float alpha = fexp2(mrow[r] - mnew);
            mrow[r] = mnew;
            float p0 = fexp2(s0 - mnew), p1 = fexp2(s1 - mnew);
            float p2 = fexp2(s2 - mnew), p3 = fexp2(s3 - mnew);
            p[0][r] = p0; p[1][r] = p1; p[2][r] = p2; p[3][r] = p3;
            lrow[r] = lrow[r] * alpha + (p0 + p1 + p2 + p3);
            accO[0][r] *= alpha; accO[1][r] *= alpha;
            accO[2][r] *= alpha; accO[3][r] *= alpha;
        }

        // P -> per-wave LDS (C layout positions) via packed bf16 cvt. No barrier.
#pragma unroll
        for (int nb = 0; nb < 4; nb++) {
            uint_t u01 = f2bf_pk(p[nb][0], p[nb][1]);
            uint_t u23 = f2bf_pk(p[nb][2], p[nb][3]);
            int col = nb * 16 + ln15;
            sP[w][(q * 4 + 0) * SKP + col] = (ushort_t)u01;
            sP[w][(q * 4 + 1) * SKP + col] = (ushort_t)(u01 >> 16);
            sP[w][(q * 4 + 2) * SKP + col] = (ushort_t)u23;
            sP[w][(q * 4 + 3) * SKP + col] = (ushort_t)(u23 >> 16);
        }

        // PV: O[16 q x 64 hd] += P[16x64] @ V[64 keys x 64 hd]
#pragma unroll
        for (int c = 0; c < 2; c++) {
            bf16x8 ap = *(const bf16x8*)(&sP[w][ln15 * SKP + c * 32 + q * 8]);
#pragma unroll
            for (int nhd = 0; nhd < 4; nhd++) {
                bf16x8 bv = *(const bf16x8*)(&sVt[(nhd * 16 + ln15) * SKP + c * 32 + q * 8]);
                accO[nhd] = __builtin_amdgcn_mfma_f32_16x16x32_bf16(ap, bv, accO[nhd], 0, 0, 0);
            }
        }
    }

    // final row-sum reduce across the 16-lane col group, then write O
    float inv[4];
#pragma unroll
    for (int r = 0; r < 4; r++) {
        float l = lrow[r];
#pragma unroll
        for (int off = 1; off < 16; off <<= 1)
            l += __shfl_xor(l, off);
        inv[r] = 1.0f / l;
    }
    ushort_t* ob = O + obase;
#pragma unroll
    for (int nhd = 0; nhd < 4; nhd++)
#pragma unroll
        for (int r = 0; r < 4; r++)
            ob[(size_t)(q0 + w * 16 + q * 4 + r) * D_ + nhd * 16 + ln15] =
                f2bf(accO[nhd][r] * inv[r]);
}

// ---------------- fused residual-add + LayerNorm (fp32 + bf16 outputs) ----------------
__global__ __launch_bounds__(256) void ln_add_kernel(
    const float* __restrict__ a, const float* __restrict__ bres,
    const float* __restrict__ g, const float* __restrict__ be,
    float* __restrict__ of, ushort_t* __restrict__ ob)
{
    int row = blockIdx.x;
    int t = threadIdx.x;
    const float* ar = a + (size_t)row * D_;
    const float* br = bres + (size_t)row * D_;
    float x[4];
    float s = 0.f, sq = 0.f;
#pragma unroll
    for (int i = 0; i < 4; i++) {
        int c = t + i * 256;
        float v = ar[c] + br[c];
        x[i] = v; s += v; sq += v * v;
    }
#pragma unroll
    for (int off = 32; off; off >>= 1) {
        s += __shfl_xor(s, off);
        sq += __shfl_xor(sq, off);
    }
    __shared__ float rs[4], rq[4];
    int w = t >> 6;
    if ((t & 63) == 0) { rs[w] = s; rq[w] = sq; }
    __syncthreads();
    s = rs[0] + rs[1] + rs[2] + rs[3];
    sq = rq[0] + rq[1] + rq[2] + rq[3];
    float mu = s * (1.0f / D_);
    float var = sq * (1.0f / D_) - mu * mu;
    float rstd = rsqrtf(var + 1e-5f);
#pragma unroll
    for (int i = 0; i < 4; i++) {
        int c = t + i * 256;
        float y = (x[i] - mu) * rstd * g[c] + be[c];
        of[(size_t)row * D_ + c] = y;
        ob[(size_t)row * D_ + c] = f2bf(y);
    }
}

extern "C" void kernel_launch(void* const* d_in, const int* in_sizes, int n_in,
                              void* d_out, int out_size, void* d_ws, size_t ws_size,
                              hipStream_t stream) {
    const int*   x    = (const int*)d_in[0];
    const float* emb  = (const float*)d_in[1];
    const float* Wq   = (const float*)d_in[2];
    const float* Wk   = (const float*)d_in[3];
    const float* Wv   = (const float*)d_in[4];
    const float* Wo   = (const float*)d_in[5];
    const float* bo   = (const float*)d_in[6];
    const float* ln1g = (const float*)d_in[7];
    const float* ln1b = (const float*)d_in[8];
    const float* W1   = (const float*)d_in[9];
    const float* b1   = (const float*)d_in[10];
    const float* W2   = (const float*)d_in[11];
    const float* b2   = (const float*)d_in[12];
    const float* ln2g = (const float*)d_in[13];
    const float* ln2b = (const float*)d_in[14];

    char* ws = (char*)d_ws;
    float*    h    = (float*)(ws + 0);             // 16 MB fp32 residual
    ushort_t* hb   = (ushort_t*)(ws + 16777216);   // 8 MB bf16 h
    float*    t0   = (float*)(ws + 25165824);      // 16 MB fp32 gemm out
    ushort_t* vtb  = (ushort_t*)(ws + 25165824);   // 8 MB V^T, overlaps t0 (dead then)
    float*    n1   = (float*)(ws + 41943040);      // 16 MB fp32 n1
    ushort_t* n1b  = (ushort_t*)(ws + 58720256);   // 8 MB bf16 n1
    ushort_t* qkvb = (ushort_t*)(ws + 67108864);   // 24 MB fused qkv [M][3072]
    ushort_t* ab   = (ushort_t*)(ws + 92274688);   // 8 MB attn out
    ushort_t* ff1  = (ushort_t*)(ws + 67108864);   // 32 MB, overlaps dead qkv/ab
    ushort_t* wqkvT= (ushort_t*)(ws + 100663296);  // 6 MB [3072][1024] bf16 (q,k,v stacked)
    ushort_t* woT  = (ushort_t*)(ws + 106954752);  // 2 MB [1024][1024]
    ushort_t* w1T  = (ushort_t*)(ws + 109051904);  // 8 MB [4096][1024]
    ushort_t* w2T  = (ushort_t*)(ws + 117440512);  // 8 MB [1024][4096]  (total 120 MB)

    embed_kernel<<<NTOK, 256, 0, stream>>>(x, emb, h, hb);

    for (int l = 0; l < L_; l++) {
        const float* Wq_l = Wq + (size_t)l * D_ * D_;
        const float* Wk_l = Wk + (size_t)l * D_ * D_;
        const float* Wv_l = Wv + (size_t)l * D_ * D_;
        const float* Wo_l = Wo + (size_t)l * D_ * D_;
        const float* bo_l = bo + (size_t)l * D_;
        const float* W1_l = W1 + (size_t)l * D_ * 4 * D_;
        const float* b1_l = b1 + (size_t)l * 4 * D_;
        const float* W2_l = W2 + (size_t)l * 4 * D_ * D_;
        const float* b2_l = b2 + (size_t)l * D_;

        // weight transpose-convert: [K][N] fp32 -> [N][K] bf16
        cvtT_kernel<<<dim3(32, 32), 256, 0, stream>>>(Wq_l, wqkvT,                 1024, 1024);
        cvtT_kernel<<<dim3(32, 32), 256, 0, stream>>>(Wk_l, wqkvT + 1024 * 1024,   1024, 1024);
        cvtT_kernel<<<dim3(32, 32), 256, 0, stream>>>(Wv_l, wqkvT + 2048 * 1024,   1024, 1024);
        cvtT_kernel<<<dim3(32, 32), 256, 0, stream>>>(Wo_l, woT,                   1024, 1024);
        cvtT_kernel<<<dim3(128, 32), 256, 0, stream>>>(W1_l, w1T,                  1024, 4096);
        cvtT_kernel<<<dim3(32, 128), 256, 0, stream>>>(W2_l, w2T,                  4096, 1024);

        // fused QKV projection: [4096,1024] @ [1024,3072] -> [4096,3072] bf16
        gemm_kernel<128><<<dim3(3072 / 128, NTOK / 128), 256, 0, stream>>>(
            hb, wqkvT, nullptr, qkvb, NTOK, 3072, 1024, GEMM_OUT_BF16);

        // V^T for the attention PV B-operand
        vt_kernel<<<dim3(S_ / 32, 64), 256, 0, stream>>>(qkvb, vtb);

        attn_kernel<<<dim3(S_ / 64, H_, B_), 256, 0, stream>>>(
            qkvb, qkvb + 1024, vtb, ab);

        gemm_kernel<64><<<dim3(1024 / 128, NTOK / 64), 256, 0, stream>>>(
            ab, woT, bo_l, t0, NTOK, 1024, 1024, 0);
        ln_add_kernel<<<NTOK, 256, 0, stream>>>(t0, h, ln1g + l * D_, ln1b + l * D_, n1, n1b);

        gemm_kernel<128><<<dim3(4096 / 128, NTOK / 128), 256, 0, stream>>>(
            n1b, w1T, b1_l, ff1, NTOK, 4096, 1024, GEMM_OUT_BF16 | GEMM_RELU);
        gemm_kernel<64><<<dim3(1024 / 128, NTOK / 64), 256, 0, stream>>>(
            ff1, w2T, b2_l, t0, NTOK, 1024, 4096, 0);

        float* of = (l == L_ - 1) ? (float*)d_out : h;
        ln_add_kernel<<<NTOK, 256, 0, stream>>>(t0, n1, ln2g + l * D_, ln2b + l * D_, of, hb);
    }
}